// Round 5
// baseline (808.561 us; speedup 1.0000x reference)
//
#include <hip/hip_runtime.h>
#include <hip/hip_bf16.h>

// NCA update, round 5: register-resident separable perception (shuffle-based),
// unified Y/H LDS region (33.8 KB -> 4 blocks/CU). Numerics identical to R2/R4.

#define CCH 16
#define HID 128
#define HH 256
#define WW 256
#define BB 32

typedef __attribute__((ext_vector_type(8))) short bf16x8;
typedef __attribute__((ext_vector_type(4))) float f32x4;
typedef __attribute__((ext_vector_type(4))) unsigned int u32x4;
typedef __attribute__((ext_vector_type(2))) unsigned int u32x2;

__device__ inline unsigned short f2bf(float f) {  // RNE
  unsigned int u = __float_as_uint(f);
  u += 0x7FFFu + ((u >> 16) & 1u);
  return (unsigned short)(u >> 16);
}
__device__ inline float bf2f(unsigned short s) {
  return __uint_as_float(((unsigned int)s) << 16);
}
__device__ inline unsigned int cvtpk2(float a, float b) {  // v_cvt_pk_bf16_f32
  union { __hip_bfloat162 h; unsigned int u; } cv;
  cv.h = __float22bfloat162_rn(make_float2(a, b));
  return cv.u;
}

// ---------------------------------------------------------------- prep
// w1p[(((pl*2+ks)*8 + mt)*64 + lane)*8 + j]; row = mt*16+(l&15),
// k = ks*32+(l>>4)*8+j; k>=48 zeroed (pairs with the dup-B-read trick).
__global__ __launch_bounds__(256) void pack_w1_kernel(
    const float* __restrict__ w1, unsigned short* __restrict__ w1p) {
  const int tid = blockIdx.x * 256 + threadIdx.x;
  if (tid >= 2048) return;
  const int l = tid & 63, m = (tid >> 6) & 7, ks = (tid >> 9) & 1,
            pl = (tid >> 10) & 1;
  const int row = m * 16 + (l & 15);
  const int kb = ks * 32 + (l >> 4) * 8;
  const size_t off = ((((size_t)pl * 2 + ks) * 8 + m) * 64 + l) * 8;
#pragma unroll
  for (int j = 0; j < 8; ++j) {
    const int k = kb + j;
    const float v = (k < 48) ? w1[row * 48 + k] : 0.0f;
    const unsigned short hi = f2bf(v);
    w1p[off + j] = (pl == 0) ? hi : f2bf(v - bf2f(hi));
  }
}

// w2p[((pl*4+ks)*64 + lane)*8 + j]; row = l&15, k = ks*32+(l>>4)*8+j.
__global__ __launch_bounds__(256) void pack_w2_kernel(
    const float* __restrict__ w2, unsigned short* __restrict__ w2p) {
  const int tid = blockIdx.x * 256 + threadIdx.x;
  if (tid >= 512) return;
  const int l = tid & 63, ks = (tid >> 6) & 3, pl = (tid >> 8) & 1;
  const int row = l & 15;
  const int kb = ks * 32 + (l >> 4) * 8;
  const size_t off = (((size_t)pl * 4 + ks) * 64 + l) * 8;
#pragma unroll
  for (int j = 0; j < 8; ++j) {
    const float v = w2[row * 128 + kb + j];
    const unsigned short hi = f2bf(v);
    w2p[off + j] = (pl == 0) ? hi : f2bf(v - bf2f(hi));
  }
}

// ---------------------------------------------------------------- main
// Block = 128 px (half row), 256 thr = 4 waves:
//   wave wv: ch-half chh = wv>>1, pixels (wv&1)*64 + lane.
// LDS 33792 B:
//   [0, 32768): unified per-pixel 256 B rows: Yh [0,96) k0..47, Yl [96,192),
//               spare [192,256); phase 3 overwrites the row with H (256 B).
//   [32768, 33792): edge/halo floats (E[]):
//     E[0..63]    edgeA[wv][e][j]   (a at lane0/lane63 of each wave)
//     E[64..127]  edgeB[wv][e][j]
//     E[128..131] edgeC[wv<2][e]    (alpha col-max at wave edges)
//     E[132..163] haloA[side][c]    (out-of-block columns)
//     E[164..195] haloB[side][c]
//     E[196..197] haloC[side]
__global__ __launch_bounds__(256, 4) void nca_mfma_kernel(
    const float* __restrict__ x, const float* __restrict__ b1,
    const float* __restrict__ b2, const unsigned short* __restrict__ w1p,
    const unsigned short* __restrict__ w2p, const int* __restrict__ fire,
    float* __restrict__ out, float* __restrict__ alpha_ws,
    unsigned char* __restrict__ pre_ws) {
  __shared__ __align__(16) unsigned char smem[33792];
  float* E = (float*)(smem + 32768);

  const int L = blockIdx.x;
  const int orig = ((L & 7) << 11) + (L >> 3);  // XCD-contiguous (16384=8*2048)
  const int b = orig >> 9;
  const int h = (orig >> 1) & 255;
  const int wt = orig & 1;
  const int tid = threadIdx.x;
  const int wv = tid >> 6, lane = tid & 63, g = lane >> 4, ln = lane & 15;
  const int chh = wv >> 1;               // channel half: 0 or 1
  const int px = (wv & 1) * 64 + lane;   // pixel 0..127
  const int gcol = wt * 128 + px;
  const int hm = (h + 255) & 255, hp = (h + 1) & 255;

  // ---- phase 1a: per-thread vertical filter (own column, 8 channels).
  float av[8], bv[8], iv[8];
  float cmax = 0.0f;
  {
    const float* xb0 = x + ((size_t)b * CCH + chh * 8) * (HH * WW);
#pragma unroll
    for (int j = 0; j < 8; ++j) {
      const float* xc = xb0 + (size_t)j * (HH * WW);
      const float t = xc[hm * WW + gcol];
      const float m = xc[h * WW + gcol];
      const float bo = xc[hp * WW + gcol];
      av[j] = 0.125f * (t + bo) + 0.25f * m;
      bv[j] = 0.125f * (bo - t);
      iv[j] = m;
      if (chh == 0 && j == 3) cmax = fmaxf(fmaxf(t, m), bo);
    }
  }

  // Edge exports (lane 0 / lane 63 of each wave).
  if (lane == 0 || lane == 63) {
    const int e = lane ? 1 : 0;
#pragma unroll
    for (int j = 0; j < 8; ++j) {
      E[wv * 16 + e * 8 + j] = av[j];
      E[64 + wv * 16 + e * 8 + j] = bv[j];
    }
    if (wv < 2) E[128 + wv * 2 + e] = cmax;
  }
  // Halo columns (outside the block): wave 1, lanes 0..31.
  if (wv == 1 && lane < 32) {
    const int side = lane >> 4;  // 0=L, 1=R
    const int c = lane & 15;
    const int gc = side ? ((wt * 128 + 128) & 255) : ((wt * 128 + 255) & 255);
    const float* xc = x + ((size_t)b * CCH + c) * (HH * WW);
    const float t = xc[hm * WW + gc];
    const float m = xc[h * WW + gc];
    const float bo = xc[hp * WW + gc];
    E[132 + side * 16 + c] = 0.125f * (t + bo) + 0.25f * m;
    E[164 + side * 16 + c] = 0.125f * (bo - t);
    if (c == 3) E[196 + side] = fmaxf(fmaxf(t, m), bo);
  }
  __syncthreads();

  // ---- phase 1b: horizontal neighbors via shuffle + edge patches -> Y.
  {
    float aL[8], aR[8], bL_[8], bR_[8];
#pragma unroll
    for (int j = 0; j < 8; ++j) {
      aL[j] = __shfl(av[j], lane - 1, 64);
      bL_[j] = __shfl(bv[j], lane - 1, 64);
      aR[j] = __shfl(av[j], lane + 1, 64);
      bR_[j] = __shfl(bv[j], lane + 1, 64);
    }
    if (lane == 0) {
      const int haloL = ((wv & 1) == 0);
      const float* sa = haloL ? (E + 132 + chh * 8) : (E + (wv - 1) * 16 + 8);
      const float* sb = haloL ? (E + 164 + chh * 8) : (E + 64 + (wv - 1) * 16 + 8);
#pragma unroll
      for (int j = 0; j < 8; ++j) { aL[j] = sa[j]; bL_[j] = sb[j]; }
    }
    if (lane == 63) {
      const int haloR = ((wv & 1) == 1);
      const float* sa = haloR ? (E + 132 + 16 + chh * 8) : (E + (wv + 1) * 16);
      const float* sb = haloR ? (E + 164 + 16 + chh * 8) : (E + 64 + (wv + 1) * 16);
#pragma unroll
      for (int j = 0; j < 8; ++j) { aR[j] = sa[j]; bR_[j] = sb[j]; }
    }

    float yv[24];
#pragma unroll
    for (int j = 0; j < 8; ++j) {
      yv[j * 3 + 0] = iv[j];
      yv[j * 3 + 1] = aR[j] - aL[j];
      yv[j * 3 + 2] = bL_[j] + 2.0f * bv[j] + bR_[j];
    }
    unsigned int hw[12], lw[12];
#pragma unroll
    for (int i = 0; i < 12; ++i) {
      const unsigned int hp2 = cvtpk2(yv[2 * i], yv[2 * i + 1]);
      hw[i] = hp2;
      const float r0 = yv[2 * i] - __uint_as_float(hp2 << 16);
      const float r1 = yv[2 * i + 1] - __uint_as_float(hp2 & 0xFFFF0000u);
      lw[i] = cvtpk2(r0, r1);
    }
    const int ybase = px * 256 + chh * 48;  // bytes; Yh row, this ch-half
    const int sw = (px & 7) << 4;
#pragma unroll
    for (int i = 0; i < 3; ++i) {
      u32x4 vh = {hw[4 * i], hw[4 * i + 1], hw[4 * i + 2], hw[4 * i + 3]};
      u32x4 vl = {lw[4 * i], lw[4 * i + 1], lw[4 * i + 2], lw[4 * i + 3]};
      *(u32x4*)(smem + ((ybase + i * 16) ^ sw)) = vh;
      *(u32x4*)(smem + ((ybase + 96 + i * 16) ^ sw)) = vl;
    }

    if (wv < 2) {  // pre-life from alpha column-max (px-1, px, px+1)
      float cl = __shfl(cmax, lane - 1, 64);
      float cr = __shfl(cmax, lane + 1, 64);
      if (lane == 0) cl = (wv == 0) ? E[196] : E[128 + 1];  // halo-L : w0.lane63
      if (lane == 63) cr = (wv == 1) ? E[197] : E[128 + 2]; // halo-R : w1.lane0
      const size_t pix = ((size_t)b * HH + h) * WW + gcol;
      pre_ws[pix] = (fmaxf(fmaxf(cl, cmax), cr) > 0.1f) ? 1 : 0;
    }
  }
  __syncthreads();

  // ---- phase 2: L1 GEMM, nt-split (wave owns px-tiles 2wv, 2wv+1).
  bf16x8 A1[8][4];  // [mt][hi-k0, hi-k1, lo-k0, lo-k1]
#pragma unroll
  for (int mt = 0; mt < 8; ++mt)
#pragma unroll
    for (int f = 0; f < 4; ++f)
      A1[mt][f] =
          *(const bf16x8*)(w1p + (((size_t)f * 8 + mt) * 64 + lane) * 8);

  f32x4 acc[8][2];
#pragma unroll
  for (int mt = 0; mt < 8; ++mt)
#pragma unroll
    for (int ni = 0; ni < 2; ++ni) acc[mt][ni] = (f32x4){0.f, 0.f, 0.f, 0.f};

#pragma unroll
  for (int ni = 0; ni < 2; ++ni) {
    const int pxb = (wv * 2 + ni) * 16 + ln;
    const int sw = (pxb & 7) << 4;
    const int base = pxb * 256;
    const int off1 = (g < 2) ? (64 + g * 16) : ((g - 2) * 16);  // dup-read pad
    const bf16x8 Bh0 = *(const bf16x8*)(smem + ((base + g * 16) ^ sw));
    const bf16x8 Bh1 = *(const bf16x8*)(smem + ((base + off1) ^ sw));
    const bf16x8 Bl0 = *(const bf16x8*)(smem + ((base + 96 + g * 16) ^ sw));
    const bf16x8 Bl1 = *(const bf16x8*)(smem + ((base + 96 + off1) ^ sw));
#pragma unroll
    for (int mt = 0; mt < 8; ++mt) {
      f32x4 a = acc[mt][ni];
      a = __builtin_amdgcn_mfma_f32_16x16x32_bf16(A1[mt][0], Bh0, a, 0, 0, 0);
      a = __builtin_amdgcn_mfma_f32_16x16x32_bf16(A1[mt][1], Bh1, a, 0, 0, 0);
      a = __builtin_amdgcn_mfma_f32_16x16x32_bf16(A1[mt][2], Bh0, a, 0, 0, 0);
      a = __builtin_amdgcn_mfma_f32_16x16x32_bf16(A1[mt][3], Bh1, a, 0, 0, 0);
      a = __builtin_amdgcn_mfma_f32_16x16x32_bf16(A1[mt][0], Bl0, a, 0, 0, 0);
      a = __builtin_amdgcn_mfma_f32_16x16x32_bf16(A1[mt][1], Bl1, a, 0, 0, 0);
      acc[mt][ni] = a;
    }
  }
  // Phases 3-5 are wave-local (each wave touches only its own px rows).

  // ---- phase 3: bias+relu -> H bf16 (swizzled), overwrites Y rows in place.
#pragma unroll
  for (int ni = 0; ni < 2; ++ni) {
    const int pxb = (wv * 2 + ni) * 16 + ln;
    const int sw = (pxb & 7) << 4;
#pragma unroll
    for (int mt = 0; mt < 8; ++mt) {
      const f32x4 bvv = *(const f32x4*)(b1 + mt * 16 + g * 4);
      const f32x4 a = acc[mt][ni];
      u32x2 hwv;
      hwv[0] = cvtpk2(fmaxf(a[0] + bvv[0], 0.f), fmaxf(a[1] + bvv[1], 0.f));
      hwv[1] = cvtpk2(fmaxf(a[2] + bvv[2], 0.f), fmaxf(a[3] + bvv[3], 0.f));
      *(u32x2*)(smem + ((pxb * 256 + (mt * 16 + g * 4) * 2) ^ sw)) = hwv;
    }
  }

  // ---- phase 4 + epilogue: L2 GEMM (K=128) + x+dx*fire, wave-local.
  bf16x8 A2[8];  // [pl*4+ks]
#pragma unroll
  for (int i = 0; i < 8; ++i)
    A2[i] = *(const bf16x8*)(w2p + ((size_t)i * 64 + lane) * 8);

  const f32x4 b2v = *(const f32x4*)(b2 + g * 4);
#pragma unroll
  for (int ni = 0; ni < 2; ++ni) {
    const int pxb = (wv * 2 + ni) * 16 + ln;
    const int sw = (pxb & 7) << 4;
    const int hbase = pxb * 256;
    f32x4 a = (f32x4){0.f, 0.f, 0.f, 0.f};
#pragma unroll
    for (int ks = 0; ks < 4; ++ks) {
      const bf16x8 Bf =
          *(const bf16x8*)(smem + ((hbase + ks * 64 + g * 16) ^ sw));
      a = __builtin_amdgcn_mfma_f32_16x16x32_bf16(A2[ks], Bf, a, 0, 0, 0);
      a = __builtin_amdgcn_mfma_f32_16x16x32_bf16(A2[4 + ks], Bf, a, 0, 0, 0);
    }
    const int wg = wt * 128 + pxb;
    const size_t pix = ((size_t)b * HH + h) * WW + wg;
    const float f = (float)fire[pix];
#pragma unroll
    for (int r = 0; r < 4; ++r) {
      const int c = g * 4 + r;
      const size_t xi = ((size_t)(b * CCH + c) * HH + h) * WW + wg;
      const float v = x[xi] + (a[r] + b2v[r]) * f;
      out[xi] = v;
      if (c == 3) alpha_ws[pix] = v;
    }
  }
}

// ---------------------------------------------------------------- life
__global__ __launch_bounds__(256) void life_mask_kernel(
    const float* __restrict__ alpha_ws, const unsigned char* __restrict__ pre_ws,
    float* __restrict__ out) {
  const int bh = blockIdx.x;
  const int b = bh >> 8;
  const int h = bh & 255;
  const int w = threadIdx.x;
  const int hm = (h + 255) & 255;
  const int hp = (h + 1) & 255;
  const int wm = (w + 255) & 255;
  const int wp = (w + 1) & 255;

  const float* ab = alpha_ws + (size_t)b * HH * WW;
  float m = ab[(size_t)hm * WW + wm];
  m = fmaxf(m, ab[(size_t)hm * WW + w]);
  m = fmaxf(m, ab[(size_t)hm * WW + wp]);
  m = fmaxf(m, ab[(size_t)h * WW + wm]);
  m = fmaxf(m, ab[(size_t)h * WW + w]);
  m = fmaxf(m, ab[(size_t)h * WW + wp]);
  m = fmaxf(m, ab[(size_t)hp * WW + wm]);
  m = fmaxf(m, ab[(size_t)hp * WW + w]);
  m = fmaxf(m, ab[(size_t)hp * WW + wp]);

  const size_t pix = ((size_t)b * HH + h) * WW + w;
  const bool post = m > 0.1f;
  const bool pre = pre_ws[pix] != 0;
  if (!(pre && post)) {
#pragma unroll
    for (int c = 0; c < CCH; ++c)
      out[((size_t)(b * CCH + c) * HH + h) * WW + w] = 0.0f;
  }
}

// ---------------------------------------------------------------- launch
extern "C" void kernel_launch(void* const* d_in, const int* in_sizes, int n_in,
                              void* d_out, int out_size, void* d_ws,
                              size_t ws_size, hipStream_t stream) {
  const float* x = (const float*)d_in[0];
  const float* w1 = (const float*)d_in[1];
  const float* b1 = (const float*)d_in[2];
  const float* w2 = (const float*)d_in[3];
  const float* b2 = (const float*)d_in[4];
  const int* fire = (const int*)d_in[5];
  float* out = (float*)d_out;

  const size_t npix = (size_t)BB * HH * WW;
  unsigned short* w1p = (unsigned short*)d_ws;
  unsigned short* w2p = (unsigned short*)((char*)d_ws + 32768);
  float* alpha_ws = (float*)((char*)d_ws + 40960);
  unsigned char* pre_ws = (unsigned char*)d_ws + 40960 + npix * sizeof(float);

  pack_w1_kernel<<<8, 256, 0, stream>>>(w1, w1p);
  pack_w2_kernel<<<2, 256, 0, stream>>>(w2, w2p);
  nca_mfma_kernel<<<BB * HH * 2, 256, 0, stream>>>(x, b1, b2, w1p, w2p, fire,
                                                   out, alpha_ws, pre_ws);
  life_mask_kernel<<<BB * HH, 256, 0, stream>>>(alpha_ws, pre_ws, out);
}

// Round 6
// 221.647 us; speedup vs baseline: 3.6480x; 3.6480x over previous
//
#include <hip/hip_runtime.h>
#include <hip/hip_bf16.h>

// NCA update, round 6: 512-thread blocks, 2D (2mt x 4nt) wave grid so the
// W1 fragments are split across waves (32 VGPR A + 32 VGPR acc per wave),
// fitting __launch_bounds__(512,4) without spills. Perception register-
// resident via shuffles (R5). Numerics identical to R2/R4/R5.

#define CCH 16
#define HID 128
#define HH 256
#define WW 256
#define BB 32

typedef __attribute__((ext_vector_type(8))) short bf16x8;
typedef __attribute__((ext_vector_type(4))) float f32x4;
typedef __attribute__((ext_vector_type(2))) unsigned int u32x2;

__device__ inline unsigned short f2bf(float f) {  // RNE
  unsigned int u = __float_as_uint(f);
  u += 0x7FFFu + ((u >> 16) & 1u);
  return (unsigned short)(u >> 16);
}
__device__ inline float bf2f(unsigned short s) {
  return __uint_as_float(((unsigned int)s) << 16);
}
__device__ inline unsigned int cvtpk2(float a, float b) {  // v_cvt_pk_bf16_f32
  union { __hip_bfloat162 h; unsigned int u; } cv;
  cv.h = __float22bfloat162_rn(make_float2(a, b));
  return cv.u;
}

// ---------------------------------------------------------------- prep
// w1p[(((pl*2+ks)*8 + mt)*64 + lane)*8 + j]; row = mt*16+(l&15),
// k = ks*32+(l>>4)*8+j; k>=48 zeroed (pairs with the dup-B-read trick).
__global__ __launch_bounds__(256) void pack_w1_kernel(
    const float* __restrict__ w1, unsigned short* __restrict__ w1p) {
  const int tid = blockIdx.x * 256 + threadIdx.x;
  if (tid >= 2048) return;
  const int l = tid & 63, m = (tid >> 6) & 7, ks = (tid >> 9) & 1,
            pl = (tid >> 10) & 1;
  const int row = m * 16 + (l & 15);
  const int kb = ks * 32 + (l >> 4) * 8;
  const size_t off = ((((size_t)pl * 2 + ks) * 8 + m) * 64 + l) * 8;
#pragma unroll
  for (int j = 0; j < 8; ++j) {
    const int k = kb + j;
    const float v = (k < 48) ? w1[row * 48 + k] : 0.0f;
    const unsigned short hi = f2bf(v);
    w1p[off + j] = (pl == 0) ? hi : f2bf(v - bf2f(hi));
  }
}

// w2p[((pl*4+ks)*64 + lane)*8 + j]; row = l&15, k = ks*32+(l>>4)*8+j.
__global__ __launch_bounds__(256) void pack_w2_kernel(
    const float* __restrict__ w2, unsigned short* __restrict__ w2p) {
  const int tid = blockIdx.x * 256 + threadIdx.x;
  if (tid >= 512) return;
  const int l = tid & 63, ks = (tid >> 6) & 3, pl = (tid >> 8) & 1;
  const int row = l & 15;
  const int kb = ks * 32 + (l >> 4) * 8;
  const size_t off = (((size_t)pl * 4 + ks) * 64 + l) * 8;
#pragma unroll
  for (int j = 0; j < 8; ++j) {
    const float v = w2[row * 128 + kb + j];
    const unsigned short hi = f2bf(v);
    w2p[off + j] = (pl == 0) ? hi : f2bf(v - bf2f(hi));
  }
}

// ---------------------------------------------------------------- main
// Block = 128 px (half row), 512 thr = 8 waves.
//   wave wv: nw = wv&1 (px half: 64 px), chq/mw = wv>>1 (4 channels / 2 mt).
// LDS 33280 B:
//   [0, 32768): per-pixel 256 B rows: Yh [0,96) k0..47, Yl [96,192);
//               phase 3 overwrites each row with H (256 B). XOR-swizzled.
//   [32768, ...): E[66] floats: EA[chq][side][4] @0, EB @32, Ec @64.
__global__ __launch_bounds__(512, 4) void nca_mfma_kernel(
    const float* __restrict__ x, const float* __restrict__ b1,
    const float* __restrict__ b2, const unsigned short* __restrict__ w1p,
    const unsigned short* __restrict__ w2p, const int* __restrict__ fire,
    float* __restrict__ out, float* __restrict__ alpha_ws,
    unsigned char* __restrict__ pre_ws) {
  __shared__ __align__(16) unsigned char smem[33280];
  float* E = (float*)(smem + 32768);

  const int L = blockIdx.x;
  const int orig = ((L & 7) << 11) + (L >> 3);  // XCD-contiguous (16384=8*2048)
  const int b = orig >> 9;
  const int h = (orig >> 1) & 255;
  const int wt = orig & 1;
  const int tid = threadIdx.x;
  const int wv = tid >> 6, lane = tid & 63, g = lane >> 4, ln = lane & 15;
  const int nw = wv & 1;        // px half: 0 -> px 0..63, 1 -> 64..127
  const int chq = wv >> 1;      // channel quarter (phase 1) / mw (phase 2)
  const int c0 = chq * 4;
  const int px = nw * 64 + lane;
  const int gcol = wt * 128 + px;
  const int hm = (h + 255) & 255, hp = (h + 1) & 255;

  // ---- phase 1a: per-thread vertical filter (own column, 4 channels).
  float av[4], bv[4], iv[4];
  float cmax = 0.0f;
  const float* xb0 = x + ((size_t)b * CCH + c0) * (HH * WW);
#pragma unroll
  for (int j = 0; j < 4; ++j) {
    const float* xc = xb0 + (size_t)j * (HH * WW);
    const float t = xc[hm * WW + gcol];
    const float m = xc[h * WW + gcol];
    const float bo = xc[hp * WW + gcol];
    av[j] = 0.125f * (t + bo) + 0.25f * m;
    bv[j] = 0.125f * (bo - t);
    iv[j] = m;
    if (chq == 0 && j == 3) cmax = fmaxf(fmaxf(t, m), bo);
  }

  // Halo columns (outside the block), kept in the edge lanes' registers.
  float haA[4], haB[4], hc = 0.0f;
  const bool haloL = (nw == 0 && lane == 0), haloR = (nw == 1 && lane == 63);
  if (haloL || haloR) {
    const int gc = haloR ? ((wt * 128 + 128) & 255) : ((wt * 128 + 255) & 255);
#pragma unroll
    for (int j = 0; j < 4; ++j) {
      const float* xc = xb0 + (size_t)j * (HH * WW);
      const float t = xc[hm * WW + gc];
      const float m = xc[h * WW + gc];
      const float bo = xc[hp * WW + gc];
      haA[j] = 0.125f * (t + bo) + 0.25f * m;
      haB[j] = 0.125f * (bo - t);
      if (chq == 0 && j == 3) hc = fmaxf(fmaxf(t, m), bo);
    }
  }
  // Edge exports at the nw boundary (px63 <-> px64), per channel quarter.
  if (lane == 63 && nw == 0) {
#pragma unroll
    for (int j = 0; j < 4; ++j) {
      E[chq * 8 + j] = av[j];
      E[32 + chq * 8 + j] = bv[j];
    }
    if (chq == 0) E[64] = cmax;
  }
  if (lane == 0 && nw == 1) {
#pragma unroll
    for (int j = 0; j < 4; ++j) {
      E[chq * 8 + 4 + j] = av[j];
      E[32 + chq * 8 + 4 + j] = bv[j];
    }
    if (chq == 0) E[65] = cmax;
  }
  __syncthreads();

  // ---- phase 1b: horizontal neighbors via shuffle -> split-bf16 Y.
  {
    float aL[4], aR[4], bL_[4], bR_[4];
#pragma unroll
    for (int j = 0; j < 4; ++j) {
      aL[j] = __shfl(av[j], lane - 1, 64);
      bL_[j] = __shfl(bv[j], lane - 1, 64);
      aR[j] = __shfl(av[j], lane + 1, 64);
      bR_[j] = __shfl(bv[j], lane + 1, 64);
    }
    if (lane == 0) {
#pragma unroll
      for (int j = 0; j < 4; ++j) {
        aL[j] = (nw == 0) ? haA[j] : E[chq * 8 + j];
        bL_[j] = (nw == 0) ? haB[j] : E[32 + chq * 8 + j];
      }
    }
    if (lane == 63) {
#pragma unroll
      for (int j = 0; j < 4; ++j) {
        aR[j] = (nw == 1) ? haA[j] : E[chq * 8 + 4 + j];
        bR_[j] = (nw == 1) ? haB[j] : E[32 + chq * 8 + 4 + j];
      }
    }

    float yv[12];
#pragma unroll
    for (int j = 0; j < 4; ++j) {
      yv[j * 3 + 0] = iv[j];
      yv[j * 3 + 1] = aR[j] - aL[j];
      yv[j * 3 + 2] = bL_[j] + 2.0f * bv[j] + bR_[j];
    }
    unsigned int hw[6], lw[6];
#pragma unroll
    for (int i = 0; i < 6; ++i) {
      const unsigned int hp2 = cvtpk2(yv[2 * i], yv[2 * i + 1]);
      hw[i] = hp2;
      const float r0 = yv[2 * i] - __uint_as_float(hp2 << 16);
      const float r1 = yv[2 * i + 1] - __uint_as_float(hp2 & 0xFFFF0000u);
      lw[i] = cvtpk2(r0, r1);
    }
    const int ybase = px * 256 + c0 * 6;  // bytes; 8-aligned chunks below
    const int sw = (px & 7) << 4;
#pragma unroll
    for (int i = 0; i < 3; ++i) {
      u32x2 vh = {hw[2 * i], hw[2 * i + 1]};
      u32x2 vl = {lw[2 * i], lw[2 * i + 1]};
      *(u32x2*)(smem + ((ybase + i * 8) ^ sw)) = vh;
      *(u32x2*)(smem + ((ybase + 96 + i * 8) ^ sw)) = vl;
    }

    if (chq == 0) {  // pre-life from alpha column-max (px-1, px, px+1)
      float cl = __shfl(cmax, lane - 1, 64);
      float cr = __shfl(cmax, lane + 1, 64);
      if (lane == 0) cl = (nw == 0) ? hc : E[64];
      if (lane == 63) cr = (nw == 1) ? hc : E[65];
      const size_t pix = ((size_t)b * HH + h) * WW + gcol;
      pre_ws[pix] = (fmaxf(fmaxf(cl, cmax), cr) > 0.1f) ? 1 : 0;
    }
  }
  __syncthreads();

  // ---- phase 2: L1 GEMM. Wave grid: mw = chq (2 mt), nw (4 nt).
  bf16x8 A1[2][4];  // [mi][hi-k0, hi-k1, lo-k0, lo-k1]
#pragma unroll
  for (int mi = 0; mi < 2; ++mi)
#pragma unroll
    for (int f = 0; f < 4; ++f)
      A1[mi][f] = *(const bf16x8*)(
          w1p + (((size_t)f * 8 + (chq * 2 + mi)) * 64 + lane) * 8);

  f32x4 acc[2][4];
#pragma unroll
  for (int mi = 0; mi < 2; ++mi)
#pragma unroll
    for (int ni = 0; ni < 4; ++ni) acc[mi][ni] = (f32x4){0.f, 0.f, 0.f, 0.f};

#pragma unroll
  for (int ni = 0; ni < 4; ++ni) {
    const int pxb = (nw * 4 + ni) * 16 + ln;
    const int sw = (pxb & 7) << 4;
    const int base = pxb * 256;
    const int off1 = (g < 2) ? (64 + g * 16) : ((g - 2) * 16);  // dup-read pad
    const bf16x8 Bh0 = *(const bf16x8*)(smem + ((base + g * 16) ^ sw));
    const bf16x8 Bh1 = *(const bf16x8*)(smem + ((base + off1) ^ sw));
    const bf16x8 Bl0 = *(const bf16x8*)(smem + ((base + 96 + g * 16) ^ sw));
    const bf16x8 Bl1 = *(const bf16x8*)(smem + ((base + 96 + off1) ^ sw));
#pragma unroll
    for (int mi = 0; mi < 2; ++mi) {
      f32x4 a = acc[mi][ni];
      a = __builtin_amdgcn_mfma_f32_16x16x32_bf16(A1[mi][0], Bh0, a, 0, 0, 0);
      a = __builtin_amdgcn_mfma_f32_16x16x32_bf16(A1[mi][1], Bh1, a, 0, 0, 0);
      a = __builtin_amdgcn_mfma_f32_16x16x32_bf16(A1[mi][2], Bh0, a, 0, 0, 0);
      a = __builtin_amdgcn_mfma_f32_16x16x32_bf16(A1[mi][3], Bh1, a, 0, 0, 0);
      a = __builtin_amdgcn_mfma_f32_16x16x32_bf16(A1[mi][0], Bl0, a, 0, 0, 0);
      a = __builtin_amdgcn_mfma_f32_16x16x32_bf16(A1[mi][1], Bl1, a, 0, 0, 0);
      acc[mi][ni] = a;
    }
  }
  __syncthreads();  // all Y reads done before H overwrites

  // ---- phase 3: bias+relu -> H bf16 (swizzled), overwrites Y rows.
#pragma unroll
  for (int mi = 0; mi < 2; ++mi) {
    const int hid0 = (chq * 2 + mi) * 16 + g * 4;
    const f32x4 b1v = *(const f32x4*)(b1 + hid0);
#pragma unroll
    for (int ni = 0; ni < 4; ++ni) {
      const int pxb = (nw * 4 + ni) * 16 + ln;
      const int sw = (pxb & 7) << 4;
      const f32x4 a = acc[mi][ni];
      u32x2 hwv;
      hwv[0] = cvtpk2(fmaxf(a[0] + b1v[0], 0.f), fmaxf(a[1] + b1v[1], 0.f));
      hwv[1] = cvtpk2(fmaxf(a[2] + b1v[2], 0.f), fmaxf(a[3] + b1v[3], 0.f));
      *(u32x2*)(smem + ((pxb * 256 + hid0 * 2) ^ sw)) = hwv;
    }
  }
  __syncthreads();  // H complete before cross-wave reads

  // ---- phase 4 + epilogue: L2 GEMM (K=128) + x+dx*fire. Wave owns tile wv.
  bf16x8 A2[8];  // [pl*4+ks]
#pragma unroll
  for (int i = 0; i < 8; ++i)
    A2[i] = *(const bf16x8*)(w2p + ((size_t)i * 64 + lane) * 8);

  {
    const int pxb = wv * 16 + ln;
    const int sw = (pxb & 7) << 4;
    const int hbase = pxb * 256;
    f32x4 a = (f32x4){0.f, 0.f, 0.f, 0.f};
#pragma unroll
    for (int ks = 0; ks < 4; ++ks) {
      const bf16x8 Bf =
          *(const bf16x8*)(smem + ((hbase + ks * 64 + g * 16) ^ sw));
      a = __builtin_amdgcn_mfma_f32_16x16x32_bf16(A2[ks], Bf, a, 0, 0, 0);
      a = __builtin_amdgcn_mfma_f32_16x16x32_bf16(A2[4 + ks], Bf, a, 0, 0, 0);
    }
    const f32x4 b2v = *(const f32x4*)(b2 + g * 4);
    const int wg = wt * 128 + pxb;
    const size_t pix = ((size_t)b * HH + h) * WW + wg;
    const float f = (float)fire[pix];
#pragma unroll
    for (int r = 0; r < 4; ++r) {
      const int c = g * 4 + r;
      const size_t xi = ((size_t)(b * CCH + c) * HH + h) * WW + wg;
      const float v = x[xi] + (a[r] + b2v[r]) * f;
      out[xi] = v;
      if (c == 3) alpha_ws[pix] = v;
    }
  }
}

// ---------------------------------------------------------------- life
__global__ __launch_bounds__(256) void life_mask_kernel(
    const float* __restrict__ alpha_ws, const unsigned char* __restrict__ pre_ws,
    float* __restrict__ out) {
  const int bh = blockIdx.x;
  const int b = bh >> 8;
  const int h = bh & 255;
  const int w = threadIdx.x;
  const int hm = (h + 255) & 255;
  const int hp = (h + 1) & 255;
  const int wm = (w + 255) & 255;
  const int wp = (w + 1) & 255;

  const float* ab = alpha_ws + (size_t)b * HH * WW;
  float m = ab[(size_t)hm * WW + wm];
  m = fmaxf(m, ab[(size_t)hm * WW + w]);
  m = fmaxf(m, ab[(size_t)hm * WW + wp]);
  m = fmaxf(m, ab[(size_t)h * WW + wm]);
  m = fmaxf(m, ab[(size_t)h * WW + w]);
  m = fmaxf(m, ab[(size_t)h * WW + wp]);
  m = fmaxf(m, ab[(size_t)hp * WW + wm]);
  m = fmaxf(m, ab[(size_t)hp * WW + w]);
  m = fmaxf(m, ab[(size_t)hp * WW + wp]);

  const size_t pix = ((size_t)b * HH + h) * WW + w;
  const bool post = m > 0.1f;
  const bool pre = pre_ws[pix] != 0;
  if (!(pre && post)) {
#pragma unroll
    for (int c = 0; c < CCH; ++c)
      out[((size_t)(b * CCH + c) * HH + h) * WW + w] = 0.0f;
  }
}

// ---------------------------------------------------------------- launch
extern "C" void kernel_launch(void* const* d_in, const int* in_sizes, int n_in,
                              void* d_out, int out_size, void* d_ws,
                              size_t ws_size, hipStream_t stream) {
  const float* x = (const float*)d_in[0];
  const float* w1 = (const float*)d_in[1];
  const float* b1 = (const float*)d_in[2];
  const float* w2 = (const float*)d_in[3];
  const float* b2 = (const float*)d_in[4];
  const int* fire = (const int*)d_in[5];
  float* out = (float*)d_out;

  const size_t npix = (size_t)BB * HH * WW;
  unsigned short* w1p = (unsigned short*)d_ws;
  unsigned short* w2p = (unsigned short*)((char*)d_ws + 32768);
  float* alpha_ws = (float*)((char*)d_ws + 40960);
  unsigned char* pre_ws = (unsigned char*)d_ws + 40960 + npix * sizeof(float);

  pack_w1_kernel<<<8, 256, 0, stream>>>(w1, w1p);
  pack_w2_kernel<<<2, 256, 0, stream>>>(w2, w2p);
  nca_mfma_kernel<<<BB * HH * 2, 512, 0, stream>>>(x, b1, b2, w1p, w2p, fire,
                                                   out, alpha_ws, pre_ws);
  life_mask_kernel<<<BB * HH, 256, 0, stream>>>(alpha_ws, pre_ws, out);
}